// Round 3
// baseline (33727.585 us; speedup 1.0000x reference)
//
#include <hip/hip_runtime.h>
#include <math.h>

#define LAYERS 8
#define C 384
#define NH 8
#define NE 4
#define TD 256
#define NV 256
#define WIN 64
#define MM 56
#define HD 48
#define BB 64
#define TT 256
#define NT (BB*TT)
#define N3C 1152
#define FF 1536
#define KV 312
#define SCALE_QK 0.14433756729740643f

static __device__ __forceinline__ float wsum(float v){
#pragma unroll
  for(int o=32;o;o>>=1) v += __shfl_xor(v,o);
  return v;
}
static __device__ __forceinline__ float wmax(float v){
#pragma unroll
  for(int o=32;o;o>>=1) v = fmaxf(v,__shfl_xor(v,o));
  return v;
}

// ---------------- embed ----------------
__global__ void k_embed(const int* __restrict__ tokens, const float* __restrict__ tok_emb,
                        const float* __restrict__ pos_emb, float* __restrict__ x){
  int idx = blockIdx.x*256 + threadIdx.x;
  if (idx >= NT*C) return;
  int t = idx / C, c = idx - t*C;
  x[idx] = tok_emb[tokens[t]*C + c] + pos_emb[(t % TT)*C + c];
}

// ---------------- layernorm (wave per row, fp32) ----------------
__global__ void k_ln(const float* __restrict__ in, const float* __restrict__ w,
                     const float* __restrict__ b, float* __restrict__ out){
  int row = blockIdx.x*4 + (threadIdx.x>>6);
  int lane = threadIdx.x & 63;
  const float* xr = in + (size_t)row*C;
  float v[6]; float s = 0.f;
#pragma unroll
  for(int i=0;i<6;i++){ v[i]=xr[lane+64*i]; s+=v[i]; }
  s = wsum(s);
  float mu = s*(1.f/C);
  float q=0.f;
#pragma unroll
  for(int i=0;i<6;i++){ float d=v[i]-mu; q+=d*d; }
  q = wsum(q);
  float inv = rsqrtf(q*(1.f/C)+1e-5f);
  float* orow = out + (size_t)row*C;
#pragma unroll
  for(int i=0;i<6;i++){ int c=lane+64*i; orow[c] = (v[i]-mu)*inv*w[c]+b[c]; }
}

// ---------------- fp32 GEMM: 128x128 tile, BK=16, 256 thr, 8x8/thread ----------------
// C = act(A@W + bias); A [M][Kn] (opt. row-indirected), W [Kn][ldB] row-major.
// IDXC: Cout[ridx[row]] += wsel[ridx[row]*NE] * val   (MoE scatter-accumulate)
// ACT: 0 none, 1 tanh, 2 exact gelu
template<int ACT, bool ACCUM, bool IDXA, bool IDXC>
__global__ __launch_bounds__(256) void k_gemm(
    const float* __restrict__ A, const float* __restrict__ W,
    const float* __restrict__ bias,
    const int* __restrict__ ridx, const int* __restrict__ cntp,
    const float* __restrict__ wsel,
    float* __restrict__ Cout, int Nn, int Kn, int ldB, int ldC)
{
  const int Mn = cntp ? *cntp : NT;
  const int bm = (int)blockIdx.y<<7, bn = (int)blockIdx.x<<7;
  if (bm >= Mn) return;
  __shared__ __attribute__((aligned(16))) float As[16][132]; // As[k][m]
  __shared__ __attribute__((aligned(16))) float Bs[16][132]; // Bs[k][n]
  const int tid = threadIdx.x;
  const int tx = tid&15, ty = tid>>4;
  const int arow = tid>>1, ah = tid&1;        // A staging: row, 8-k half
  const int brow = tid>>4, bc = (tid&15)<<3;  // B staging: k-row, col*8
  int r0 = bm + arow; if (r0 > Mn-1) r0 = Mn-1;
  const int agr = IDXA ? ridx[r0] : r0;
  const float* Arow = A + (size_t)agr*Kn + (ah<<3);
  float acc[8][8] = {};
  for (int k0=0; k0<Kn; k0+=16){
    float4 a0 = *(const float4*)(Arow + k0);
    float4 a1 = *(const float4*)(Arow + k0 + 4);
    const int kk0 = ah<<3;
    As[kk0+0][arow]=a0.x; As[kk0+1][arow]=a0.y; As[kk0+2][arow]=a0.z; As[kk0+3][arow]=a0.w;
    As[kk0+4][arow]=a1.x; As[kk0+5][arow]=a1.y; As[kk0+6][arow]=a1.z; As[kk0+7][arow]=a1.w;
    const float* Wr = W + (size_t)(k0+brow)*ldB + bn + bc;
    *(float4*)&Bs[brow][bc]   = *(const float4*)(Wr);
    *(float4*)&Bs[brow][bc+4] = *(const float4*)(Wr+4);
    __syncthreads();
#pragma unroll
    for (int kk=0;kk<16;kk++){
      float a[8], b[8];
      *(float4*)&a[0] = *(const float4*)&As[kk][ty<<3];
      *(float4*)&a[4] = *(const float4*)&As[kk][(ty<<3)+4];
      *(float4*)&b[0] = *(const float4*)&Bs[kk][tx<<3];
      *(float4*)&b[4] = *(const float4*)&Bs[kk][(tx<<3)+4];
#pragma unroll
      for(int i=0;i<8;i++)
#pragma unroll
        for(int j=0;j<8;j++) acc[i][j] += a[i]*b[j];
    }
    __syncthreads();
  }
#pragma unroll
  for(int i=0;i<8;i++){
    const int row = bm + (ty<<3) + i;
    if (row < Mn){
      const int grow = IDXC ? ridx[row] : row;
      const float wsc = IDXC ? wsel[(size_t)grow*NE] : 1.f;
      float* crow = Cout + (size_t)grow*ldC + bn + (tx<<3);
#pragma unroll
      for(int j=0;j<8;j++){
        float val = acc[i][j] + (bias ? bias[bn + (tx<<3) + j] : 0.f);
        if (ACT==1) val = tanhf(val);
        if (ACT==2) val = 0.5f*val*(1.0f+erff(val*0.70710678118654752f));
        if (IDXC)       crow[j] += wsc*val;
        else if (ACCUM) crow[j] += val;
        else            crow[j]  = val;
      }
    }
  }
}

// ---------------- attention: block per (b,head); K in padded LDS, V from L2 ----------------
__global__ __launch_bounds__(256) void k_attn(const float* __restrict__ qkv,
    const float* __restrict__ mem, const float* __restrict__ gate,
    float* __restrict__ y){
  __shared__ float ks[KV][49];   // pad 49: odd stride -> conflict-free column reads
  __shared__ float att[4][KV];
  int b = blockIdx.x >> 3, hh = blockIdx.x & 7;
  int tid = threadIdx.x;
  for(int idx=tid; idx<KV*HD; idx+=256){
    int j = idx/HD, d = idx - j*HD;
    ks[j][d] = (j < MM) ? mem[j*C + hh*HD + d]
                        : qkv[(size_t)(b*TT + j - MM)*N3C + C + hh*HD + d];
  }
  __syncthreads();
  int wave = tid>>6, lane = tid&63;
  for(int i=wave;i<TT;i+=4){
    const float* qrow = qkv + (size_t)(b*TT+i)*N3C + hh*HD;
    float q[HD];
#pragma unroll
    for(int d=0;d<HD;d++) q[d]=qrow[d];
    float sc[5]; float mx = -1e30f;
#pragma unroll
    for(int jj=0;jj<5;jj++){
      int j = lane + jj*64;
      float s = -1e30f;
      if (j < KV){
        bool valid = (j < MM) || ((j-MM) <= i && (i-(j-MM)) <= WIN);
        if (valid){
          float dot=0.f;
#pragma unroll
          for(int d=0;d<HD;d++) dot += q[d]*ks[j][d];
          s = dot*SCALE_QK;
        }
      }
      sc[jj]=s; mx = fmaxf(mx,s);
    }
    mx = wmax(mx);
    float ls=0.f;
#pragma unroll
    for(int jj=0;jj<5;jj++){
      int j = lane + jj*64;
      float p = (sc[jj] > -1e29f) ? expf(sc[jj]-mx) : 0.f;
      ls += p;
      if (j < KV) att[wave][j] = p;
    }
    ls = wsum(ls);
    float inv = 1.f/ls;
    if (lane < HD){
      float acc=0.f;
      for(int j=0;j<MM;j++) acc += att[wave][j]*mem[j*C + hh*HD + lane];
      int lo = (i>WIN ? i-WIN : 0), hi = i;
      const float* vbase = qkv + (size_t)(b*TT)*N3C + 2*C + hh*HD + lane;
      for(int j=lo;j<=hi;j++) acc += att[wave][MM+j]*vbase[(size_t)j*N3C];
      y[(size_t)(b*TT+i)*C + hh*HD + lane] = acc*inv*gate[hh*HD+lane];
    }
  }
}

// ---------------- router: wave per token ----------------
__global__ void k_gate(const float* __restrict__ h2, const float* __restrict__ gw,
                       const float* __restrict__ gb, float* __restrict__ wout){
  int row = blockIdx.x*4 + (threadIdx.x>>6);
  int lane = threadIdx.x & 63;
  const float* hr = h2 + (size_t)row*C;
  float a0=0,a1=0,a2=0,a3=0;
  for(int c=lane;c<C;c+=64){
    float hv = hr[c];
    const float* g = gw + c*NE;
    a0+=hv*g[0]; a1+=hv*g[1]; a2+=hv*g[2]; a3+=hv*g[3];
  }
  a0=wsum(a0); a1=wsum(a1); a2=wsum(a2); a3=wsum(a3);
  if (lane==0){
    float p[4]={a0+gb[0],a1+gb[1],a2+gb[2],a3+gb[3]};
    float m = fmaxf(fmaxf(p[0],p[1]),fmaxf(p[2],p[3]));
    float s=0.f;
#pragma unroll
    for(int e=0;e<4;e++){ p[e]=expf(p[e]-m); s+=p[e]; }
#pragma unroll
    for(int e=0;e<4;e++) p[e] /= s;
    int i1=0;
    for(int e=1;e<4;e++) if(p[e]>p[i1]) i1=e;
    int i2=-1;
    for(int e=0;e<4;e++){ if(e==i1) continue; if(i2<0 || p[e]>p[i2]) i2=e; }
    float invs = 1.f/(p[i1]+p[i2]+1e-9f);
    float wv[4]={0.f,0.f,0.f,0.f};
    wv[i1]=p[i1]*invs; wv[i2]=p[i2]*invs;
    float* o = wout + (size_t)row*NE;
    o[0]=wv[0]; o[1]=wv[1]; o[2]=wv[2]; o[3]=wv[3];
  }
}

// ---------------- deterministic per-expert compaction (1 block per expert) ----------------
__global__ __launch_bounds__(256) void k_compact(const float* __restrict__ wbuf,
    int* __restrict__ ridx, int* __restrict__ cnt){
  int e = blockIdx.x;
  int tid = threadIdx.x;
  int wave = tid>>6, lane = tid&63;
  __shared__ int wsum_s[4];
  __shared__ int base_s;
  if (tid==0) base_s = 0;
  __syncthreads();
  for(int t0=0; t0<NT; t0+=256){
    int t = t0 + tid;
    bool f = wbuf[(size_t)t*NE + e] > 0.f;
    unsigned long long bal = __ballot(f);
    int pre = __popcll(bal & ((1ull<<lane)-1ull));
    if (lane==0) wsum_s[wave] = __popcll(bal);
    __syncthreads();
    int off = 0;
#pragma unroll
    for(int w2=0;w2<4;w2++) if (w2 < wave) off += wsum_s[w2];
    int tot = wsum_s[0]+wsum_s[1]+wsum_s[2]+wsum_s[3];
    int b0 = base_s;
    if (f) ridx[(size_t)e*NT + b0 + off + pre] = t;
    __syncthreads();
    if (tid==0) base_s = b0 + tot;
    __syncthreads();
  }
  if (tid==0) cnt[e] = base_s;
}

extern "C" void kernel_launch(void* const* d_in, const int* in_sizes, int n_in,
                              void* d_out, int out_size, void* d_ws, size_t ws_size,
                              hipStream_t stream){
  (void)in_sizes; (void)n_in; (void)out_size; (void)ws_size;
  const int*   tokens  = (const int*)d_in[0];
  const float* tok_emb = (const float*)d_in[1];
  const float* pos_emb = (const float*)d_in[2];
  const float* mem     = (const float*)d_in[3];
  const float* ln1_w   = (const float*)d_in[4];
  const float* ln1_b   = (const float*)d_in[5];
  const float* qkv_w   = (const float*)d_in[6];
  const float* qkv_b   = (const float*)d_in[7];
  const float* proj_w  = (const float*)d_in[8];
  const float* proj_b  = (const float*)d_in[9];
  const float* attn_g  = (const float*)d_in[10];
  const float* th1_w   = (const float*)d_in[11];
  const float* th1_b   = (const float*)d_in[12];
  const float* th2_w   = (const float*)d_in[13];
  const float* th2_b   = (const float*)d_in[14];
  const float* ln2_w   = (const float*)d_in[15];
  const float* ln2_b   = (const float*)d_in[16];
  const float* gate_w  = (const float*)d_in[17];
  const float* gate_b  = (const float*)d_in[18];
  const float* e1_w    = (const float*)d_in[19];
  const float* e1_b    = (const float*)d_in[20];
  const float* e2_w    = (const float*)d_in[21];
  const float* e2_b    = (const float*)d_in[22];
  const float* lnf_w   = (const float*)d_in[23];
  const float* lnf_b   = (const float*)d_in[24];
  const float* head_w  = (const float*)d_in[25];
  const float* head_b  = (const float*)d_in[26];
  float* out = (float*)d_out;

  char* p = (char*)d_ws;
  float* x    = (float*)p; p += (size_t)NT*C*4;     // residual stream
  float* h    = (float*)p; p += (size_t)NT*C*4;     // LN outputs
  float* qkvb = (float*)p; p += (size_t)NT*N3C*4;   // qkv
  float* sh   = (float*)p; p += (size_t)NT*C*4;     // y / t1 / he-chunk (aliased)
  float* wbuf = (float*)p; p += (size_t)NT*NE*4;    // router weights
  int*   ridx = (int*)p;   p += (size_t)NE*NT*4;    // per-expert token lists
  int*   cnt  = (int*)p;   p += 64;                 // per-expert counts

  dim3 b256(256);
  k_embed<<<dim3((NT*C+255)/256), b256, 0, stream>>>(tokens, tok_emb, pos_emb, x);
  for(int l=0;l<LAYERS;l++){
    k_ln<<<dim3(NT/4), b256, 0, stream>>>(x, ln1_w+l*C, ln1_b+l*C, h);
    k_gemm<0,false,false,false><<<dim3(N3C/128, NT/128), b256, 0, stream>>>(
        h, qkv_w+(size_t)l*C*N3C, qkv_b+(size_t)l*N3C, nullptr, nullptr, nullptr,
        qkvb, N3C, C, N3C, N3C);
    k_attn<<<dim3(BB*NH), b256, 0, stream>>>(qkvb, mem, attn_g+(size_t)l*C, sh);
    k_gemm<0,true,false,false><<<dim3(C/128, NT/128), b256, 0, stream>>>(
        sh, proj_w+(size_t)l*C*C, proj_b+(size_t)l*C, nullptr, nullptr, nullptr,
        x, C, C, C, C);
    k_gemm<1,false,false,false><<<dim3(TD/128, NT/128), b256, 0, stream>>>(
        x, th1_w+(size_t)l*C*TD, th1_b+(size_t)l*TD, nullptr, nullptr, nullptr,
        sh, TD, C, TD, TD);
    k_gemm<0,true,false,false><<<dim3(C/128, NT/128), b256, 0, stream>>>(
        sh, th2_w+(size_t)l*TD*C, th2_b+(size_t)l*C, nullptr, nullptr, nullptr,
        x, C, TD, C, C);
    k_ln<<<dim3(NT/4), b256, 0, stream>>>(x, ln2_w+l*C, ln2_b+l*C, h);
    k_gate<<<dim3(NT/4), b256, 0, stream>>>(h, gate_w+(size_t)l*C*NE, gate_b+(size_t)l*NE, wbuf);
    k_compact<<<dim3(NE), b256, 0, stream>>>(wbuf, ridx, cnt);
    for(int e=0;e<NE;e++){
      const float* e1wb = e1_w + (size_t)(l*NE+e)*C*FF;
      const float* e1bb = e1_b + (size_t)(l*NE+e)*FF;
      const float* e2wb = e2_w + (size_t)(l*NE+e)*FF*C;
      const float* e2bb = e2_b + (size_t)(l*NE+e)*C;
      for(int f0=0; f0<FF; f0+=384){
        // he_chunk = gelu(h[sel] @ e1[:, f0:f0+384] + e1_b[f0:...])
        k_gemm<2,false,true,false><<<dim3(3, NT/128), b256, 0, stream>>>(
            h, e1wb + f0, e1bb + f0, ridx + (size_t)e*NT, cnt + e, nullptr,
            sh, 384, C, FF, 384);
        // x[sel] += w_e * (he_chunk @ e2[f0:f0+384, :] (+ e2_b on first chunk))
        k_gemm<0,true,false,true><<<dim3(3, NT/128), b256, 0, stream>>>(
            sh, e2wb + (size_t)f0*C, (f0==0 ? e2bb : nullptr),
            ridx + (size_t)e*NT, cnt + e, wbuf + e,
            x, C, 384, C, C);
      }
    }
  }
  k_ln<<<dim3(NT/4), b256, 0, stream>>>(x, lnf_w, lnf_b, h);
  k_gemm<0,false,false,false><<<dim3(NV/128, NT/128), b256, 0, stream>>>(
      h, head_w, head_b, nullptr, nullptr, nullptr, out, NV, C, NV, NV);
}

// Round 4
// 33724.622 us; speedup vs baseline: 1.0001x; 1.0001x over previous
//
#include <hip/hip_runtime.h>
#include <math.h>

#define LAYERS 8
#define C 384
#define NH 8
#define NE 4
#define TD 256
#define NV 256
#define WIN 64
#define MM 56
#define HD 48
#define BB 64
#define TT 256
#define NT (BB*TT)
#define N3C 1152
#define FF 1536
#define KV 312
#define SCALE_QK 0.14433756729740643f

static __device__ __forceinline__ float wsum(float v){
#pragma unroll
  for(int o=32;o;o>>=1) v += __shfl_xor(v,o);
  return v;
}
static __device__ __forceinline__ float wmax(float v){
#pragma unroll
  for(int o=32;o;o>>=1) v = fmaxf(v,__shfl_xor(v,o));
  return v;
}

// ---------------- embed ----------------
__global__ void k_embed(const int* __restrict__ tokens, const float* __restrict__ tok_emb,
                        const float* __restrict__ pos_emb, float* __restrict__ x){
  int idx = blockIdx.x*256 + threadIdx.x;
  if (idx >= NT*C) return;
  int t = idx / C, c = idx - t*C;
  x[idx] = tok_emb[tokens[t]*C + c] + pos_emb[(t % TT)*C + c];
}

// ---------------- layernorm (wave per row, fp32) ----------------
__global__ void k_ln(const float* __restrict__ in, const float* __restrict__ w,
                     const float* __restrict__ b, float* __restrict__ out){
  int row = blockIdx.x*4 + (threadIdx.x>>6);
  int lane = threadIdx.x & 63;
  const float* xr = in + (size_t)row*C;
  float v[6]; float s = 0.f;
#pragma unroll
  for(int i=0;i<6;i++){ v[i]=xr[lane+64*i]; s+=v[i]; }
  s = wsum(s);
  float mu = s*(1.f/C);
  float q=0.f;
#pragma unroll
  for(int i=0;i<6;i++){ float d=v[i]-mu; q+=d*d; }
  q = wsum(q);
  float inv = rsqrtf(q*(1.f/C)+1e-5f);
  float* orow = out + (size_t)row*C;
#pragma unroll
  for(int i=0;i<6;i++){ int c=lane+64*i; orow[c] = (v[i]-mu)*inv*w[c]+b[c]; }
}

// ---------------- fp32 GEMM: 128x128 tile, BK=16, 256 thr, 8x8/thread ----------------
// C = act(A@W + bias); A [M][Kn] (opt. row-indirected), W [Kn][ldB] row-major.
// IDXC: Cout[ridx[row]] += wsel[ridx[row]*NE] * val   (MoE scatter-accumulate)
// ACT: 0 none, 1 tanh, 2 exact gelu
template<int ACT, bool ACCUM, bool IDXA, bool IDXC>
__global__ __launch_bounds__(256) void k_gemm(
    const float* __restrict__ A, const float* __restrict__ W,
    const float* __restrict__ bias,
    const int* __restrict__ ridx, const int* __restrict__ cntp,
    const float* __restrict__ wsel,
    float* __restrict__ Cout, int Nn, int Kn, int ldB, int ldC)
{
  const int Mn = cntp ? *cntp : NT;
  const int bm = (int)blockIdx.y<<7, bn = (int)blockIdx.x<<7;
  if (bm >= Mn) return;
  __shared__ __attribute__((aligned(16))) float As[16][132]; // As[k][m]
  __shared__ __attribute__((aligned(16))) float Bs[16][132]; // Bs[k][n]
  const int tid = threadIdx.x;
  const int tx = tid&15, ty = tid>>4;
  const int arow = tid>>1, ah = tid&1;        // A staging: row, 8-k half
  const int brow = tid>>4, bc = (tid&15)<<3;  // B staging: k-row, col*8
  int r0 = bm + arow; if (r0 > Mn-1) r0 = Mn-1;
  const int agr = IDXA ? ridx[r0] : r0;
  const float* Arow = A + (size_t)agr*Kn + (ah<<3);
  float acc[8][8] = {};
  for (int k0=0; k0<Kn; k0+=16){
    float4 a0 = *(const float4*)(Arow + k0);
    float4 a1 = *(const float4*)(Arow + k0 + 4);
    const int kk0 = ah<<3;
    As[kk0+0][arow]=a0.x; As[kk0+1][arow]=a0.y; As[kk0+2][arow]=a0.z; As[kk0+3][arow]=a0.w;
    As[kk0+4][arow]=a1.x; As[kk0+5][arow]=a1.y; As[kk0+6][arow]=a1.z; As[kk0+7][arow]=a1.w;
    const float* Wr = W + (size_t)(k0+brow)*ldB + bn + bc;
    *(float4*)&Bs[brow][bc]   = *(const float4*)(Wr);
    *(float4*)&Bs[brow][bc+4] = *(const float4*)(Wr+4);
    __syncthreads();
#pragma unroll
    for (int kk=0;kk<16;kk++){
      float a[8], b[8];
      *(float4*)&a[0] = *(const float4*)&As[kk][ty<<3];
      *(float4*)&a[4] = *(const float4*)&As[kk][(ty<<3)+4];
      *(float4*)&b[0] = *(const float4*)&Bs[kk][tx<<3];
      *(float4*)&b[4] = *(const float4*)&Bs[kk][(tx<<3)+4];
#pragma unroll
      for(int i=0;i<8;i++)
#pragma unroll
        for(int j=0;j<8;j++) acc[i][j] += a[i]*b[j];
    }
    __syncthreads();
  }
#pragma unroll
  for(int i=0;i<8;i++){
    const int row = bm + (ty<<3) + i;
    if (row < Mn){
      const int grow = IDXC ? ridx[row] : row;
      const float wsc = IDXC ? wsel[(size_t)grow*NE] : 1.f;
      float* crow = Cout + (size_t)grow*ldC + bn + (tx<<3);
#pragma unroll
      for(int j=0;j<8;j++){
        float val = acc[i][j] + (bias ? bias[bn + (tx<<3) + j] : 0.f);
        if (ACT==1) val = tanhf(val);
        if (ACT==2) val = 0.5f*val*(1.0f+erff(val*0.70710678118654752f));
        if (IDXC)       crow[j] += wsc*val;
        else if (ACCUM) crow[j] += val;
        else            crow[j]  = val;
      }
    }
  }
}

// ---------------- attention: block per (b,head); K in padded LDS, V from L2 ----------------
__global__ __launch_bounds__(256) void k_attn(const float* __restrict__ qkv,
    const float* __restrict__ mem, const float* __restrict__ gate,
    float* __restrict__ y){
  __shared__ float ks[KV][49];   // pad 49: odd stride -> conflict-free column reads
  __shared__ float att[4][KV];
  int b = blockIdx.x >> 3, hh = blockIdx.x & 7;
  int tid = threadIdx.x;
  for(int idx=tid; idx<KV*HD; idx+=256){
    int j = idx/HD, d = idx - j*HD;
    ks[j][d] = (j < MM) ? mem[j*C + hh*HD + d]
                        : qkv[(size_t)(b*TT + j - MM)*N3C + C + hh*HD + d];
  }
  __syncthreads();
  int wave = tid>>6, lane = tid&63;
  for(int i=wave;i<TT;i+=4){
    const float* qrow = qkv + (size_t)(b*TT+i)*N3C + hh*HD;
    float q[HD];
#pragma unroll
    for(int d=0;d<HD;d++) q[d]=qrow[d];
    float sc[5]; float mx = -1e30f;
#pragma unroll
    for(int jj=0;jj<5;jj++){
      int j = lane + jj*64;
      float s = -1e30f;
      if (j < KV){
        bool valid = (j < MM) || ((j-MM) <= i && (i-(j-MM)) <= WIN);
        if (valid){
          float dot=0.f;
#pragma unroll
          for(int d=0;d<HD;d++) dot += q[d]*ks[j][d];
          s = dot*SCALE_QK;
        }
      }
      sc[jj]=s; mx = fmaxf(mx,s);
    }
    mx = wmax(mx);
    float ls=0.f;
#pragma unroll
    for(int jj=0;jj<5;jj++){
      int j = lane + jj*64;
      float p = (sc[jj] > -1e29f) ? expf(sc[jj]-mx) : 0.f;
      ls += p;
      if (j < KV) att[wave][j] = p;
    }
    ls = wsum(ls);
    float inv = 1.f/ls;
    if (lane < HD){
      float acc=0.f;
      for(int j=0;j<MM;j++) acc += att[wave][j]*mem[j*C + hh*HD + lane];
      int lo = (i>WIN ? i-WIN : 0), hi = i;
      const float* vbase = qkv + (size_t)(b*TT)*N3C + 2*C + hh*HD + lane;
      for(int j=lo;j<=hi;j++) acc += att[wave][MM+j]*vbase[(size_t)j*N3C];
      y[(size_t)(b*TT+i)*C + hh*HD + lane] = acc*inv*gate[hh*HD+lane];
    }
  }
}

// ---------------- router: wave per token ----------------
__global__ void k_gate(const float* __restrict__ h2, const float* __restrict__ gw,
                       const float* __restrict__ gb, float* __restrict__ wout){
  int row = blockIdx.x*4 + (threadIdx.x>>6);
  int lane = threadIdx.x & 63;
  const float* hr = h2 + (size_t)row*C;
  float a0=0,a1=0,a2=0,a3=0;
  for(int c=lane;c<C;c+=64){
    float hv = hr[c];
    const float* g = gw + c*NE;
    a0+=hv*g[0]; a1+=hv*g[1]; a2+=hv*g[2]; a3+=hv*g[3];
  }
  a0=wsum(a0); a1=wsum(a1); a2=wsum(a2); a3=wsum(a3);
  if (lane==0){
    float p[4]={a0+gb[0],a1+gb[1],a2+gb[2],a3+gb[3]};
    float m = fmaxf(fmaxf(p[0],p[1]),fmaxf(p[2],p[3]));
    float s=0.f;
#pragma unroll
    for(int e=0;e<4;e++){ p[e]=expf(p[e]-m); s+=p[e]; }
#pragma unroll
    for(int e=0;e<4;e++) p[e] /= s;
    int i1=0;
    for(int e=1;e<4;e++) if(p[e]>p[i1]) i1=e;
    int i2=-1;
    for(int e=0;e<4;e++){ if(e==i1) continue; if(i2<0 || p[e]>p[i2]) i2=e; }
    float invs = 1.f/(p[i1]+p[i2]+1e-9f);
    float wv[4]={0.f,0.f,0.f,0.f};
    wv[i1]=p[i1]*invs; wv[i2]=p[i2]*invs;
    float* o = wout + (size_t)row*NE;
    o[0]=wv[0]; o[1]=wv[1]; o[2]=wv[2]; o[3]=wv[3];
  }
}

// ---------------- deterministic per-expert compaction (1 block per expert) ----------------
__global__ __launch_bounds__(256) void k_compact(const float* __restrict__ wbuf,
    int* __restrict__ ridx, int* __restrict__ cnt){
  int e = blockIdx.x;
  int tid = threadIdx.x;
  int wave = tid>>6, lane = tid&63;
  __shared__ int wsum_s[4];
  __shared__ int base_s;
  if (tid==0) base_s = 0;
  __syncthreads();
  for(int t0=0; t0<NT; t0+=256){
    int t = t0 + tid;
    bool f = wbuf[(size_t)t*NE + e] > 0.f;
    unsigned long long bal = __ballot(f);
    int pre = __popcll(bal & ((1ull<<lane)-1ull));
    if (lane==0) wsum_s[wave] = __popcll(bal);
    __syncthreads();
    int off = 0;
#pragma unroll
    for(int w2=0;w2<4;w2++) if (w2 < wave) off += wsum_s[w2];
    int tot = wsum_s[0]+wsum_s[1]+wsum_s[2]+wsum_s[3];
    int b0 = base_s;
    if (f) ridx[(size_t)e*NT + b0 + off + pre] = t;
    __syncthreads();
    if (tid==0) base_s = b0 + tot;
    __syncthreads();
  }
  if (tid==0) cnt[e] = base_s;
}

extern "C" void kernel_launch(void* const* d_in, const int* in_sizes, int n_in,
                              void* d_out, int out_size, void* d_ws, size_t ws_size,
                              hipStream_t stream){
  (void)in_sizes; (void)n_in; (void)out_size; (void)ws_size;
  const int*   tokens  = (const int*)d_in[0];
  const float* tok_emb = (const float*)d_in[1];
  const float* pos_emb = (const float*)d_in[2];
  const float* mem     = (const float*)d_in[3];
  const float* ln1_w   = (const float*)d_in[4];
  const float* ln1_b   = (const float*)d_in[5];
  const float* qkv_w   = (const float*)d_in[6];
  const float* qkv_b   = (const float*)d_in[7];
  const float* proj_w  = (const float*)d_in[8];
  const float* proj_b  = (const float*)d_in[9];
  const float* attn_g  = (const float*)d_in[10];
  const float* th1_w   = (const float*)d_in[11];
  const float* th1_b   = (const float*)d_in[12];
  const float* th2_w   = (const float*)d_in[13];
  const float* th2_b   = (const float*)d_in[14];
  const float* ln2_w   = (const float*)d_in[15];
  const float* ln2_b   = (const float*)d_in[16];
  const float* gate_w  = (const float*)d_in[17];
  const float* gate_b  = (const float*)d_in[18];
  const float* e1_w    = (const float*)d_in[19];
  const float* e1_b    = (const float*)d_in[20];
  const float* e2_w    = (const float*)d_in[21];
  const float* e2_b    = (const float*)d_in[22];
  const float* lnf_w   = (const float*)d_in[23];
  const float* lnf_b   = (const float*)d_in[24];
  const float* head_w  = (const float*)d_in[25];
  const float* head_b  = (const float*)d_in[26];
  float* out = (float*)d_out;

  char* p = (char*)d_ws;
  float* x    = (float*)p; p += (size_t)NT*C*4;     // residual stream
  float* h    = (float*)p; p += (size_t)NT*C*4;     // LN outputs
  float* qkvb = (float*)p; p += (size_t)NT*N3C*4;   // qkv
  float* sh   = (float*)p; p += (size_t)NT*C*4;     // y / t1 / he-chunk (aliased)
  float* wbuf = (float*)p; p += (size_t)NT*NE*4;    // router weights
  int*   ridx = (int*)p;   p += (size_t)NE*NT*4;    // per-expert token lists
  int*   cnt  = (int*)p;   p += 64;                 // per-expert counts

  dim3 b256(256);
  k_embed<<<dim3((NT*C+255)/256), b256, 0, stream>>>(tokens, tok_emb, pos_emb, x);
  for(int l=0;l<LAYERS;l++){
    k_ln<<<dim3(NT/4), b256, 0, stream>>>(x, ln1_w+l*C, ln1_b+l*C, h);
    k_gemm<0,false,false,false><<<dim3(N3C/128, NT/128), b256, 0, stream>>>(
        h, qkv_w+(size_t)l*C*N3C, qkv_b+(size_t)l*N3C, nullptr, nullptr, nullptr,
        qkvb, N3C, C, N3C, N3C);
    k_attn<<<dim3(BB*NH), b256, 0, stream>>>(qkvb, mem, attn_g+(size_t)l*C, sh);
    k_gemm<0,true,false,false><<<dim3(C/128, NT/128), b256, 0, stream>>>(
        sh, proj_w+(size_t)l*C*C, proj_b+(size_t)l*C, nullptr, nullptr, nullptr,
        x, C, C, C, C);
    k_gemm<1,false,false,false><<<dim3(TD/128, NT/128), b256, 0, stream>>>(
        x, th1_w+(size_t)l*C*TD, th1_b+(size_t)l*TD, nullptr, nullptr, nullptr,
        sh, TD, C, TD, TD);
    k_gemm<0,true,false,false><<<dim3(C/128, NT/128), b256, 0, stream>>>(
        sh, th2_w+(size_t)l*TD*C, th2_b+(size_t)l*C, nullptr, nullptr, nullptr,
        x, C, TD, C, C);
    k_ln<<<dim3(NT/4), b256, 0, stream>>>(x, ln2_w+l*C, ln2_b+l*C, h);
    k_gate<<<dim3(NT/4), b256, 0, stream>>>(h, gate_w+(size_t)l*C*NE, gate_b+(size_t)l*NE, wbuf);
    k_compact<<<dim3(NE), b256, 0, stream>>>(wbuf, ridx, cnt);
    for(int e=0;e<NE;e++){
      const float* e1wb = e1_w + (size_t)(l*NE+e)*C*FF;
      const float* e1bb = e1_b + (size_t)(l*NE+e)*FF;
      const float* e2wb = e2_w + (size_t)(l*NE+e)*FF*C;
      const float* e2bb = e2_b + (size_t)(l*NE+e)*C;
      for(int f0=0; f0<FF; f0+=384){
        // he_chunk = gelu(h[sel] @ e1[:, f0:f0+384] + e1_b[f0:...])
        k_gemm<2,false,true,false><<<dim3(3, NT/128), b256, 0, stream>>>(
            h, e1wb + f0, e1bb + f0, ridx + (size_t)e*NT, cnt + e, nullptr,
            sh, 384, C, FF, 384);
        // x[sel] += w_e * (he_chunk @ e2[f0:f0+384, :] (+ e2_b on first chunk))
        k_gemm<0,true,false,true><<<dim3(3, NT/128), b256, 0, stream>>>(
            sh, e2wb + (size_t)f0*C, (f0==0 ? e2bb : nullptr),
            ridx + (size_t)e*NT, cnt + e, wbuf + e,
            x, C, 384, C, C);
      }
    }
  }
  k_ln<<<dim3(NT/4), b256, 0, stream>>>(x, lnf_w, lnf_b, h);
  k_gemm<0,false,false,false><<<dim3(NV/128, NT/128), b256, 0, stream>>>(
      h, head_w, head_b, nullptr, nullptr, nullptr, out, NV, C, NV, NV);
}

// Round 5
// 21072.943 us; speedup vs baseline: 1.6005x; 1.6004x over previous
//
#include <hip/hip_runtime.h>
#include <math.h>

#define LAYERS 8
#define C 384
#define NH 8
#define NE 4
#define TD 256
#define NV 256
#define WIN 64
#define MM 56
#define HD 48
#define BB 64
#define TT 256
#define NT (BB*TT)
#define N3C 1152
#define FF 1536
#define KV 312
#define FCH 256              // MoE FF chunk width
#define SCALE_QK 0.14433756729740643f

static __device__ __forceinline__ float wsum(float v){
#pragma unroll
  for(int o=32;o;o>>=1) v += __shfl_xor(v,o);
  return v;
}
static __device__ __forceinline__ float wmax(float v){
#pragma unroll
  for(int o=32;o;o>>=1) v = fmaxf(v,__shfl_xor(v,o));
  return v;
}

// ---------------- embed ----------------
__global__ void k_embed(const int* __restrict__ tokens, const float* __restrict__ tok_emb,
                        const float* __restrict__ pos_emb, float* __restrict__ x){
  int idx = blockIdx.x*256 + threadIdx.x;
  if (idx >= NT*C) return;
  int t = idx / C, c = idx - t*C;
  x[idx] = tok_emb[tokens[t]*C + c] + pos_emb[(t % TT)*C + c];
}

// ---------------- layernorm (wave per row) ----------------
__global__ void k_ln(const float* __restrict__ in, const float* __restrict__ w,
                     const float* __restrict__ b, float* __restrict__ out){
  int row = blockIdx.x*4 + (threadIdx.x>>6);
  int lane = threadIdx.x & 63;
  const float* xr = in + (size_t)row*C;
  float v[6]; float s = 0.f;
#pragma unroll
  for(int i=0;i<6;i++){ v[i]=xr[lane+64*i]; s+=v[i]; }
  s = wsum(s);
  float mu = s*(1.f/C);
  float q=0.f;
#pragma unroll
  for(int i=0;i<6;i++){ float d=v[i]-mu; q+=d*d; }
  q = wsum(q);
  float inv = rsqrtf(q*(1.f/C)+1e-5f);
  float* orow = out + (size_t)row*C;
#pragma unroll
  for(int i=0;i<6;i++){ int c=lane+64*i; orow[c] = (v[i]-mu)*inv*w[c]+b[c]; }
}

// ---------------- fp32 GEMM: 128x128 tile, BK=16, 256 thr, 8x8/thread ----------------
// Register double-buffered staging (prefetch next K-tile's globals before compute).
// MOE: blockIdx.z = expert; Mn=cnt[z]; W/bias += z*stride; C rows offset by ebase[z];
//      GATHER: A rows via ridx[z*NT + r]; else A rows offset by ebase[z].
// ACT: 0 none, 1 tanh, 2 exact gelu
template<int ACT, bool ACCUM, bool MOE, bool GATHER>
__global__ __launch_bounds__(256) void k_gemm(
    const float* __restrict__ A, const float* __restrict__ W,
    const float* __restrict__ bias,
    const int* __restrict__ ridx, const int* __restrict__ cnt,
    const int* __restrict__ ebase, size_t sWz, size_t sBz,
    float* __restrict__ Cout, int Kn, int ldA, int ldB, int ldC)
{
  const int z = MOE ? (int)blockIdx.z : 0;
  const int Mn = MOE ? cnt[z] : NT;
  const int bm = (int)blockIdx.y<<7, bn = (int)blockIdx.x<<7;
  if (bm >= Mn) return;
  if (MOE){
    W += (size_t)z*sWz;
    if (bias) bias += (size_t)z*sBz;
    const int eb = ebase[z];
    if (!GATHER) A += (size_t)eb*ldA;
    Cout += (size_t)eb*ldC;
  }
  __shared__ __attribute__((aligned(16))) float As[16][132]; // As[k][m]
  __shared__ __attribute__((aligned(16))) float Bs[16][132]; // Bs[k][n]
  const int tid = threadIdx.x;
  const int tx = tid&15, ty = tid>>4;
  const int arow = tid>>1, ah = tid&1;        // A staging: row, k-half(8)
  const int brow = tid>>4, bc = (tid&15)<<3;  // B staging: k-row, col*8
  int r0 = bm + arow; if (r0 >= Mn) r0 = Mn-1;
  const int agr = GATHER ? ridx[(size_t)z*NT + r0] : r0;
  const float* Arow = A + (size_t)agr*ldA + (ah<<3);
  const float* Wrow = W + (size_t)brow*ldB + bn + bc;
  float4 a0 = *(const float4*)(Arow);
  float4 a1 = *(const float4*)(Arow+4);
  float4 b0 = *(const float4*)(Wrow);
  float4 b1 = *(const float4*)(Wrow+4);
  float acc[8][8] = {};
  for (int k0=0; k0<Kn; k0+=16){
    const int kk0 = ah<<3;
    As[kk0+0][arow]=a0.x; As[kk0+1][arow]=a0.y; As[kk0+2][arow]=a0.z; As[kk0+3][arow]=a0.w;
    As[kk0+4][arow]=a1.x; As[kk0+5][arow]=a1.y; As[kk0+6][arow]=a1.z; As[kk0+7][arow]=a1.w;
    *(float4*)&Bs[brow][bc]   = b0;
    *(float4*)&Bs[brow][bc+4] = b1;
    if (k0+16 < Kn){  // prefetch next tile (latency hidden under compute below)
      a0 = *(const float4*)(Arow + k0+16);
      a1 = *(const float4*)(Arow + k0+20);
      b0 = *(const float4*)(Wrow + (size_t)(k0+16)*ldB);
      b1 = *(const float4*)(Wrow + (size_t)(k0+16)*ldB + 4);
    }
    __syncthreads();
#pragma unroll
    for (int kk=0;kk<16;kk++){
      float4 aa0 = *(const float4*)&As[kk][ty<<3];
      float4 aa1 = *(const float4*)&As[kk][(ty<<3)+4];
      float4 bb0 = *(const float4*)&Bs[kk][tx<<2];
      float4 bb1 = *(const float4*)&Bs[kk][64+(tx<<2)];
      float av[8]={aa0.x,aa0.y,aa0.z,aa0.w,aa1.x,aa1.y,aa1.z,aa1.w};
      float bv[8]={bb0.x,bb0.y,bb0.z,bb0.w,bb1.x,bb1.y,bb1.z,bb1.w};
#pragma unroll
      for(int i=0;i<8;i++)
#pragma unroll
        for(int j=0;j<8;j++) acc[i][j] += av[i]*bv[j];
    }
    __syncthreads();
  }
  // epilogue: rows ty*8+i, cols {bn+tx*4, bn+64+tx*4}
  const int c0 = bn + (tx<<2), c1 = c0 + 64;
  float4 bias0 = make_float4(0,0,0,0), bias1 = make_float4(0,0,0,0);
  if (bias){ bias0 = *(const float4*)&bias[c0]; bias1 = *(const float4*)&bias[c1]; }
#pragma unroll
  for(int i=0;i<8;i++){
    const int row = bm + (ty<<3) + i;
    if (row < Mn){
      float v[8];
      v[0]=acc[i][0]+bias0.x; v[1]=acc[i][1]+bias0.y; v[2]=acc[i][2]+bias0.z; v[3]=acc[i][3]+bias0.w;
      v[4]=acc[i][4]+bias1.x; v[5]=acc[i][5]+bias1.y; v[6]=acc[i][6]+bias1.z; v[7]=acc[i][7]+bias1.w;
#pragma unroll
      for(int j=0;j<8;j++){
        if (ACT==1) v[j] = tanhf(v[j]);
        if (ACT==2) v[j] = 0.5f*v[j]*(1.0f+erff(v[j]*0.70710678118654752f));
      }
      float* p0 = Cout + (size_t)row*ldC + c0;
      float* p1 = Cout + (size_t)row*ldC + c1;
      float4 w0 = make_float4(v[0],v[1],v[2],v[3]);
      float4 w1 = make_float4(v[4],v[5],v[6],v[7]);
      if (ACCUM){
        float4 o0 = *(const float4*)p0, o1 = *(const float4*)p1;
        w0.x+=o0.x; w0.y+=o0.y; w0.z+=o0.z; w0.w+=o0.w;
        w1.x+=o1.x; w1.y+=o1.y; w1.z+=o1.z; w1.w+=o1.w;
      }
      *(float4*)p0 = w0;
      *(float4*)p1 = w1;
    }
  }
}

// ---------------- attention: block per (b,head); K in padded LDS, V from L2 ----------------
__global__ __launch_bounds__(256) void k_attn(const float* __restrict__ qkv,
    const float* __restrict__ mem, const float* __restrict__ gate,
    float* __restrict__ y){
  __shared__ float ks[KV][49];
  __shared__ float att[4][KV];
  int b = blockIdx.x >> 3, hh = blockIdx.x & 7;
  int tid = threadIdx.x;
  for(int idx=tid; idx<KV*HD; idx+=256){
    int j = idx/HD, d = idx - j*HD;
    ks[j][d] = (j < MM) ? mem[j*C + hh*HD + d]
                        : qkv[(size_t)(b*TT + j - MM)*N3C + C + hh*HD + d];
  }
  __syncthreads();
  int wave = tid>>6, lane = tid&63;
  for(int i=wave;i<TT;i+=4){
    const float* qrow = qkv + (size_t)(b*TT+i)*N3C + hh*HD;
    float q[HD];
#pragma unroll
    for(int d=0;d<HD;d++) q[d]=qrow[d];
    float sc[5]; float mx = -1e30f;
#pragma unroll
    for(int jj=0;jj<5;jj++){
      int j = lane + jj*64;
      float s = -1e30f;
      if (j < KV){
        bool valid = (j < MM) || ((j-MM) <= i && (i-(j-MM)) <= WIN);
        if (valid){
          float dot=0.f;
#pragma unroll
          for(int d=0;d<HD;d++) dot += q[d]*ks[j][d];
          s = dot*SCALE_QK;
        }
      }
      sc[jj]=s; mx = fmaxf(mx,s);
    }
    mx = wmax(mx);
    float ls=0.f;
#pragma unroll
    for(int jj=0;jj<5;jj++){
      int j = lane + jj*64;
      float p = (sc[jj] > -1e29f) ? expf(sc[jj]-mx) : 0.f;
      ls += p;
      if (j < KV) att[wave][j] = p;
    }
    ls = wsum(ls);
    float inv = 1.f/ls;
    if (lane < HD){
      float acc=0.f;
      for(int j=0;j<MM;j++) acc += att[wave][j]*mem[j*C + hh*HD + lane];
      int lo = (i>WIN ? i-WIN : 0), hi = i;
      const float* vbase = qkv + (size_t)(b*TT)*N3C + 2*C + hh*HD + lane;
      for(int j=lo;j<=hi;j++) acc += att[wave][MM+j]*vbase[(size_t)j*N3C];
      y[(size_t)(b*TT+i)*C + hh*HD + lane] = acc*inv*gate[hh*HD+lane];
    }
  }
}

// ---------------- router ----------------
__global__ void k_gate(const float* __restrict__ h2, const float* __restrict__ gw,
                       const float* __restrict__ gb, float* __restrict__ wout){
  int row = blockIdx.x*4 + (threadIdx.x>>6);
  int lane = threadIdx.x & 63;
  const float* hr = h2 + (size_t)row*C;
  float a0=0,a1=0,a2=0,a3=0;
  for(int c=lane;c<C;c+=64){
    float hv = hr[c];
    const float* g = gw + c*NE;
    a0+=hv*g[0]; a1+=hv*g[1]; a2+=hv*g[2]; a3+=hv*g[3];
  }
  a0=wsum(a0); a1=wsum(a1); a2=wsum(a2); a3=wsum(a3);
  if (lane==0){
    float p[4]={a0+gb[0],a1+gb[1],a2+gb[2],a3+gb[3]};
    float m = fmaxf(fmaxf(p[0],p[1]),fmaxf(p[2],p[3]));
    float s=0.f;
#pragma unroll
    for(int e=0;e<4;e++){ p[e]=expf(p[e]-m); s+=p[e]; }
#pragma unroll
    for(int e=0;e<4;e++) p[e] /= s;
    int i1=0;
    for(int e=1;e<4;e++) if(p[e]>p[i1]) i1=e;
    int i2=-1;
    for(int e=0;e<4;e++){ if(e==i1) continue; if(i2<0 || p[e]>p[i2]) i2=e; }
    float invs = 1.f/(p[i1]+p[i2]+1e-9f);
    float wv[4]={0.f,0.f,0.f,0.f};
    wv[i1]=p[i1]*invs; wv[i2]=p[i2]*invs;
    float* o = wout + (size_t)row*NE;
    o[0]=wv[0]; o[1]=wv[1]; o[2]=wv[2]; o[3]=wv[3];
  }
}

// ---------------- per-expert compaction + inverse map ----------------
__global__ __launch_bounds__(256) void k_compact(const float* __restrict__ wbuf,
    int* __restrict__ ridx, int* __restrict__ posmap, int* __restrict__ cnt){
  int e = blockIdx.x;
  int tid = threadIdx.x;
  int wave = tid>>6, lane = tid&63;
  __shared__ int wsum_s[4];
  __shared__ int base_s;
  if (tid==0) base_s = 0;
  __syncthreads();
  for(int t0=0; t0<NT; t0+=256){
    int t = t0 + tid;
    bool f = wbuf[(size_t)t*NE + e] > 0.f;
    unsigned long long bal = __ballot(f);
    int pre = __popcll(bal & ((1ull<<lane)-1ull));
    if (lane==0) wsum_s[wave] = __popcll(bal);
    __syncthreads();
    int off = 0;
#pragma unroll
    for(int w2=0;w2<4;w2++) if (w2 < wave) off += wsum_s[w2];
    int tot = wsum_s[0]+wsum_s[1]+wsum_s[2]+wsum_s[3];
    int b0 = base_s;
    int pos = b0 + off + pre;
    if (f) ridx[(size_t)e*NT + pos] = t;
    posmap[(size_t)t*NE + e] = f ? pos : -1;
    __syncthreads();
    if (tid==0) base_s = b0 + tot;
    __syncthreads();
  }
  if (tid==0) cnt[e] = base_s;
}

__global__ void k_prefix(const int* __restrict__ cnt, int* __restrict__ ebase){
  if (threadIdx.x==0 && blockIdx.x==0){
    int s=0;
#pragma unroll
    for(int e=0;e<NE;e++){ ebase[e]=s; s+=cnt[e]; }
  }
}

// ---------------- MoE gather: x[t] += sum_e w[t,e] * ye[ebase[e]+pos(t,e)] ----------------
__global__ __launch_bounds__(256) void k_moe_gather(const float* __restrict__ ye,
    const float* __restrict__ wbuf, const int* __restrict__ posmap,
    const int* __restrict__ ebase, float* __restrict__ x){
  int idx = blockIdx.x*256 + threadIdx.x;      // NT * 96 float4-granules
  if (idx >= NT*(C/4)) return;
  int t = idx/(C/4), c4 = (idx - t*(C/4))*4;
  float4 acc = *(const float4*)(x + (size_t)t*C + c4);
#pragma unroll
  for(int e=0;e<NE;e++){
    int p = posmap[(size_t)t*NE + e];
    if (p >= 0){
      float w = wbuf[(size_t)t*NE + e];
      float4 yv = *(const float4*)(ye + (size_t)(ebase[e]+p)*C + c4);
      acc.x += w*yv.x; acc.y += w*yv.y; acc.z += w*yv.z; acc.w += w*yv.w;
    }
  }
  *(float4*)(x + (size_t)t*C + c4) = acc;
}

extern "C" void kernel_launch(void* const* d_in, const int* in_sizes, int n_in,
                              void* d_out, int out_size, void* d_ws, size_t ws_size,
                              hipStream_t stream){
  (void)in_sizes; (void)n_in; (void)out_size; (void)ws_size;
  const int*   tokens  = (const int*)d_in[0];
  const float* tok_emb = (const float*)d_in[1];
  const float* pos_emb = (const float*)d_in[2];
  const float* mem     = (const float*)d_in[3];
  const float* ln1_w   = (const float*)d_in[4];
  const float* ln1_b   = (const float*)d_in[5];
  const float* qkv_w   = (const float*)d_in[6];
  const float* qkv_b   = (const float*)d_in[7];
  const float* proj_w  = (const float*)d_in[8];
  const float* proj_b  = (const float*)d_in[9];
  const float* attn_g  = (const float*)d_in[10];
  const float* th1_w   = (const float*)d_in[11];
  const float* th1_b   = (const float*)d_in[12];
  const float* th2_w   = (const float*)d_in[13];
  const float* th2_b   = (const float*)d_in[14];
  const float* ln2_w   = (const float*)d_in[15];
  const float* ln2_b   = (const float*)d_in[16];
  const float* gate_w  = (const float*)d_in[17];
  const float* gate_b  = (const float*)d_in[18];
  const float* e1_w    = (const float*)d_in[19];
  const float* e1_b    = (const float*)d_in[20];
  const float* e2_w    = (const float*)d_in[21];
  const float* e2_b    = (const float*)d_in[22];
  const float* lnf_w   = (const float*)d_in[23];
  const float* lnf_b   = (const float*)d_in[24];
  const float* head_w  = (const float*)d_in[25];
  const float* head_b  = (const float*)d_in[26];
  float* out = (float*)d_out;

  char* p = (char*)d_ws;
  float* x    = (float*)p; p += (size_t)NT*C*4;       // residual
  float* h    = (float*)p; p += (size_t)NT*C*4;       // LN out
  float* qkvb = (float*)p; p += (size_t)NT*N3C*4;     // qkv; aliased by ye (2NT*C)
  float* sh   = (float*)p; p += (size_t)2*NT*FCH*4;   // y / t1 / he_all (33.5MB region)
  float* wbuf = (float*)p; p += (size_t)NT*NE*4;
  int*   ridx = (int*)p;   p += (size_t)NE*NT*4;
  int*   posm = (int*)p;   p += (size_t)NT*NE*4;
  int*   cnt  = (int*)p;   p += 64;
  int*   ebase= (int*)p;   p += 64;
  float* ye   = qkvb;                                  // 2NT*C fits in NT*N3C
  float* he   = sh;

  dim3 b256(256);
  k_embed<<<dim3((NT*C+255)/256), b256, 0, stream>>>(tokens, tok_emb, pos_emb, x);
  for(int l=0;l<LAYERS;l++){
    k_ln<<<dim3(NT/4), b256, 0, stream>>>(x, ln1_w+l*C, ln1_b+l*C, h);
    k_gemm<0,false,false,false><<<dim3(N3C/128, NT/128), b256, 0, stream>>>(
        h, qkv_w+(size_t)l*C*N3C, qkv_b+(size_t)l*N3C, nullptr, nullptr, nullptr, 0, 0,
        qkvb, C, C, N3C, N3C);
    k_attn<<<dim3(BB*NH), b256, 0, stream>>>(qkvb, mem, attn_g+(size_t)l*C, sh);
    k_gemm<0,true,false,false><<<dim3(C/128, NT/128), b256, 0, stream>>>(
        sh, proj_w+(size_t)l*C*C, proj_b+(size_t)l*C, nullptr, nullptr, nullptr, 0, 0,
        x, C, C, C, C);
    k_gemm<1,false,false,false><<<dim3(TD/128, NT/128), b256, 0, stream>>>(
        x, th1_w+(size_t)l*C*TD, th1_b+(size_t)l*TD, nullptr, nullptr, nullptr, 0, 0,
        sh, C, C, TD, TD);
    k_gemm<0,true,false,false><<<dim3(C/128, NT/128), b256, 0, stream>>>(
        sh, th2_w+(size_t)l*TD*C, th2_b+(size_t)l*C, nullptr, nullptr, nullptr, 0, 0,
        x, TD, TD, C, C);
    k_ln<<<dim3(NT/4), b256, 0, stream>>>(x, ln2_w+l*C, ln2_b+l*C, h);
    k_gate<<<dim3(NT/4), b256, 0, stream>>>(h, gate_w+(size_t)l*C*NE, gate_b+(size_t)l*NE, wbuf);
    k_compact<<<dim3(NE), b256, 0, stream>>>(wbuf, ridx, posm, cnt);
    k_prefix<<<dim3(1), dim3(64), 0, stream>>>(cnt, ebase);
    for(int f0=0; f0<FF; f0+=FCH){
      // he = gelu(h[sel] @ e1[:, f0:f0+FCH] + e1_b)   (all experts, z-dim)
      k_gemm<2,false,true,true><<<dim3(FCH/128, NT/128, NE), b256, 0, stream>>>(
          h, e1_w + (size_t)l*NE*C*FF + f0, e1_b + (size_t)l*NE*FF + f0,
          ridx, cnt, ebase, (size_t)C*FF, (size_t)FF,
          he, C, C, FF, FCH);
      // ye (+)= he @ e2[f0:f0+FCH, :] (+ e2_b on first chunk)
      if (f0==0)
        k_gemm<0,false,true,false><<<dim3(C/128, NT/128, NE), b256, 0, stream>>>(
            he, e2_w + (size_t)l*NE*FF*C, e2_b + (size_t)l*NE*C,
            ridx, cnt, ebase, (size_t)FF*C, (size_t)C,
            ye, FCH, FCH, C, C);
      else
        k_gemm<0,true,true,false><<<dim3(C/128, NT/128, NE), b256, 0, stream>>>(
            he, e2_w + (size_t)l*NE*FF*C + (size_t)f0*C, nullptr,
            ridx, cnt, ebase, (size_t)FF*C, (size_t)C,
            ye, FCH, FCH, C, C);
    }
    k_moe_gather<<<dim3((NT*(C/4)+255)/256), b256, 0, stream>>>(ye, wbuf, posm, ebase, x);
  }
  k_ln<<<dim3(NT/4), b256, 0, stream>>>(x, lnf_w, lnf_b, h);
  k_gemm<0,false,false,false><<<dim3(NV/128, NT/128), b256, 0, stream>>>(
      h, head_w, head_b, nullptr, nullptr, nullptr, 0, 0,
      out, C, C, NV, NV);
}

// Round 6
// 14378.592 us; speedup vs baseline: 2.3457x; 1.4656x over previous
//
#include <hip/hip_runtime.h>
#include <math.h>

#define LAYERS 8
#define C 384
#define NH 8
#define NE 4
#define TD 256
#define NV 256
#define WIN 64
#define MM 56
#define HD 48
#define BB 64
#define TT 256
#define NT (BB*TT)
#define N3C 1152
#define FF 1536
#define KV 312
#define FCH 256              // MoE FF chunk width
#define SCALE_QK 0.14433756729740643f

static __device__ __forceinline__ float wsum(float v){
#pragma unroll
  for(int o=32;o;o>>=1) v += __shfl_xor(v,o);
  return v;
}

// ---------------- embed ----------------
__global__ void k_embed(const int* __restrict__ tokens, const float* __restrict__ tok_emb,
                        const float* __restrict__ pos_emb, float* __restrict__ x){
  int idx = blockIdx.x*256 + threadIdx.x;
  if (idx >= NT*C) return;
  int t = idx / C, c = idx - t*C;
  x[idx] = tok_emb[tokens[t]*C + c] + pos_emb[(t % TT)*C + c];
}

// ---------------- layernorm (wave per row) ----------------
__global__ void k_ln(const float* __restrict__ in, const float* __restrict__ w,
                     const float* __restrict__ b, float* __restrict__ out){
  int row = blockIdx.x*4 + (threadIdx.x>>6);
  int lane = threadIdx.x & 63;
  const float* xr = in + (size_t)row*C;
  float v[6]; float s = 0.f;
#pragma unroll
  for(int i=0;i<6;i++){ v[i]=xr[lane+64*i]; s+=v[i]; }
  s = wsum(s);
  float mu = s*(1.f/C);
  float q=0.f;
#pragma unroll
  for(int i=0;i<6;i++){ float d=v[i]-mu; q+=d*d; }
  q = wsum(q);
  float inv = rsqrtf(q*(1.f/C)+1e-5f);
  float* orow = out + (size_t)row*C;
#pragma unroll
  for(int i=0;i<6;i++){ int c=lane+64*i; orow[c] = (v[i]-mu)*inv*w[c]+b[c]; }
}

// ---------------- fp32 GEMM: 128xTN tile, BK=16, 256 thr ----------------
// Pipeline: barrier -> issue next-tile globals -> compute -> barrier -> LDS write.
// (Loads issued right AFTER a barrier so the pre-barrier vmcnt(0) drain lands
//  after ~2048 cycles of FMA work, not immediately after issue.)
// MOE: blockIdx.z = expert; Mn=cnt[z]; W/bias += z*stride; C rows offset ebase[z];
//      GATHER: A rows via ridx[z*NT + r]; else A rows offset by ebase[z].
// ACT: 0 none, 1 tanh, 2 exact gelu
template<int ACT, bool ACCUM, bool MOE, bool GATHER, int TN>
__global__ __launch_bounds__(256) void k_gemm(
    const float* __restrict__ A, const float* __restrict__ W,
    const float* __restrict__ bias,
    const int* __restrict__ ridx, const int* __restrict__ cnt,
    const int* __restrict__ ebase, size_t sWz, size_t sBz,
    float* __restrict__ Cout, int Kn, int ldA, int ldB, int ldC)
{
  const int z = MOE ? (int)blockIdx.z : 0;
  const int Mn = MOE ? cnt[z] : NT;
  const int bm = (int)blockIdx.y<<7, bn = (int)blockIdx.x*TN;
  if (bm >= Mn) return;
  if (MOE){
    W += (size_t)z*sWz;
    if (bias) bias += (size_t)z*sBz;
    const int eb = ebase[z];
    if (!GATHER) A += (size_t)eb*ldA;
    Cout += (size_t)eb*ldC;
  }
  __shared__ __attribute__((aligned(16))) float As[16][132];
  __shared__ __attribute__((aligned(16))) float Bs[16][TN+4];
  const int tid = threadIdx.x;
  const int tx = tid&15, ty = tid>>4;
  const int arow = tid>>1, ah = tid&1;
  const int brow = tid>>4;
  const int bc = (TN==128) ? ((tid&15)<<3) : ((tid&15)<<2);
  int r0 = bm + arow; if (r0 >= Mn) r0 = Mn-1;
  const int agr = GATHER ? ridx[(size_t)z*NT + r0] : r0;
  const float* Arow = A + (size_t)agr*ldA + (ah<<3);
  const float* Wrow = W + (size_t)brow*ldB + bn + bc;
  float4 a0 = *(const float4*)(Arow);
  float4 a1 = *(const float4*)(Arow+4);
  float4 b0 = *(const float4*)(Wrow);
  float4 b1;
  if (TN==128) b1 = *(const float4*)(Wrow+4);
  {
    const int kk0 = ah<<3;
    As[kk0+0][arow]=a0.x; As[kk0+1][arow]=a0.y; As[kk0+2][arow]=a0.z; As[kk0+3][arow]=a0.w;
    As[kk0+4][arow]=a1.x; As[kk0+5][arow]=a1.y; As[kk0+6][arow]=a1.z; As[kk0+7][arow]=a1.w;
    *(float4*)&Bs[brow][bc] = b0;
    if (TN==128) *(float4*)&Bs[brow][bc+4] = b1;
  }
  constexpr int NJ = (TN==128)?8:4;
  float acc[8][NJ] = {};
  for (int k0=0; k0<Kn; k0+=16){
    __syncthreads();                       // tile k0 visible in LDS
    const bool more = (k0+16 < Kn);
    if (more){                             // issue next-tile loads AFTER barrier
      a0 = *(const float4*)(Arow + k0+16);
      a1 = *(const float4*)(Arow + k0+20);
      b0 = *(const float4*)(Wrow + (size_t)(k0+16)*ldB);
      if (TN==128) b1 = *(const float4*)(Wrow + (size_t)(k0+16)*ldB + 4);
    }
#pragma unroll
    for (int kk=0;kk<16;kk++){
      float av[8], bv[NJ];
      *(float4*)&av[0] = *(const float4*)&As[kk][ty<<3];
      *(float4*)&av[4] = *(const float4*)&As[kk][(ty<<3)+4];
      *(float4*)&bv[0] = *(const float4*)&Bs[kk][tx<<2];
      if (TN==128) *(float4*)&bv[4] = *(const float4*)&Bs[kk][64+(tx<<2)];
#pragma unroll
      for(int i=0;i<8;i++)
#pragma unroll
        for(int j=0;j<NJ;j++) acc[i][j] += av[i]*bv[j];
    }
    __syncthreads();                       // compute done; vmcnt drain hidden
    if (more){
      const int kk0 = ah<<3;
      As[kk0+0][arow]=a0.x; As[kk0+1][arow]=a0.y; As[kk0+2][arow]=a0.z; As[kk0+3][arow]=a0.w;
      As[kk0+4][arow]=a1.x; As[kk0+5][arow]=a1.y; As[kk0+6][arow]=a1.z; As[kk0+7][arow]=a1.w;
      *(float4*)&Bs[brow][bc] = b0;
      if (TN==128) *(float4*)&Bs[brow][bc+4] = b1;
    }
  }
  // epilogue: rows bm+ty*8+i; cols {bn+tx*4} and (TN=128) {bn+64+tx*4}
  const int c0 = bn + (tx<<2), c1 = c0 + 64;
  float4 bias0 = make_float4(0,0,0,0), bias1 = make_float4(0,0,0,0);
  if (bias){
    bias0 = *(const float4*)&bias[c0];
    if (TN==128) bias1 = *(const float4*)&bias[c1];
  }
#pragma unroll
  for(int i=0;i<8;i++){
    const int row = bm + (ty<<3) + i;
    if (row < Mn){
      float v[NJ];
      v[0]=acc[i][0]+bias0.x; v[1]=acc[i][1]+bias0.y; v[2]=acc[i][2]+bias0.z; v[3]=acc[i][3]+bias0.w;
      if (TN==128){ v[4]=acc[i][4]+bias1.x; v[5]=acc[i][5]+bias1.y; v[6]=acc[i][6]+bias1.z; v[7]=acc[i][7]+bias1.w; }
#pragma unroll
      for(int j=0;j<NJ;j++){
        if (ACT==1) v[j] = tanhf(v[j]);
        if (ACT==2) v[j] = 0.5f*v[j]*(1.0f+erff(v[j]*0.70710678118654752f));
      }
      float* p0 = Cout + (size_t)row*ldC + c0;
      float4 w0 = make_float4(v[0],v[1],v[2],v[3]);
      if (ACCUM){
        float4 o0 = *(const float4*)p0;
        w0.x+=o0.x; w0.y+=o0.y; w0.z+=o0.z; w0.w+=o0.w;
      }
      *(float4*)p0 = w0;
      if (TN==128){
        float* p1 = Cout + (size_t)row*ldC + c1;
        float4 w1 = make_float4(v[4],v[5],v[6],v[7]);
        if (ACCUM){
          float4 o1 = *(const float4*)p1;
          w1.x+=o1.x; w1.y+=o1.y; w1.z+=o1.z; w1.w+=o1.w;
        }
        *(float4*)p1 = w1;
      }
    }
  }
}

// ---------------- attention: block per (b,head); lane-per-query 1-pass flash ----------------
// K and V staged in LDS stride 50 (float2-aligned, odd-dword pairs -> ~conflict-free).
// Each lane owns query i = tid: online softmax (defer-max THR=8), no cross-lane ops.
__global__ __launch_bounds__(256) void k_attn(const float* __restrict__ qkv,
    const float* __restrict__ mem, const float* __restrict__ gate,
    float* __restrict__ y){
  __shared__ float ks[KV*50];
  __shared__ float vs[KV*50];
  const int b = blockIdx.x >> 3, hh = blockIdx.x & 7;
  const int tid = threadIdx.x;
  for(int idx=tid; idx<KV*24; idx+=256){
    int j = idx/24, f = (idx - j*24)*2;
    float2 kvv, vvv;
    if (j < MM){
      kvv = *(const float2*)(mem + j*C + hh*HD + f);
      vvv = kvv;
    } else {
      const float* row = qkv + (size_t)(b*TT + j - MM)*N3C + hh*HD + f;
      kvv = *(const float2*)(row + C);
      vvv = *(const float2*)(row + 2*C);
    }
    *(float2*)(ks + j*50 + f) = kvv;
    *(float2*)(vs + j*50 + f) = vvv;
  }
  __syncthreads();
  const int i = tid;                 // query index 0..255
  const float* qrow = qkv + (size_t)(b*TT+i)*N3C + hh*HD;
  float q[HD];
#pragma unroll
  for(int d2=0; d2<24; d2++){
    float2 qv = *(const float2*)(qrow + d2*2);
    q[d2*2] = qv.x; q[d2*2+1] = qv.y;
  }
  float m = -1e30f, l = 0.f;
  float acc[HD];
#pragma unroll
  for(int d=0;d<HD;d++) acc[d]=0.f;

#define ATT_STEP(JROW) {                                            \
    const float* kr = ks + (JROW)*50;                               \
    float dot = 0.f;                                                \
    _Pragma("unroll")                                               \
    for(int d2=0; d2<24; d2++){                                     \
      float2 kv2 = *(const float2*)(kr + d2*2);                     \
      dot += q[d2*2]*kv2.x + q[d2*2+1]*kv2.y;                       \
    }                                                               \
    float s = dot*SCALE_QK;                                         \
    if (s > m + 8.f){                                               \
      float f_ = __expf(m - s);                                     \
      l *= f_;                                                      \
      _Pragma("unroll")                                             \
      for(int d=0; d<HD; d++) acc[d] *= f_;                         \
      m = s;                                                        \
    }                                                               \
    float pch = __expf(s - m);                                      \
    l += pch;                                                       \
    const float* vr = vs + (JROW)*50;                               \
    _Pragma("unroll")                                               \
    for(int d2=0; d2<24; d2++){                                     \
      float2 vv2 = *(const float2*)(vr + d2*2);                     \
      acc[d2*2]   += pch*vv2.x;                                     \
      acc[d2*2+1] += pch*vv2.y;                                     \
    }                                                               \
  }

  for(int j=0; j<MM; j++) ATT_STEP(j)
  const int lo = (i > WIN) ? (i - WIN) : 0;
  for(int j=MM+lo; j<=MM+i; j++) ATT_STEP(j)
#undef ATT_STEP

  const float inv = 1.f/l;
  const float* g = gate + hh*HD;
  float* yr = y + (size_t)(b*TT+i)*C + hh*HD;
#pragma unroll
  for(int d=0;d<HD;d++) yr[d] = acc[d]*inv*g[d];
}

// ---------------- router ----------------
__global__ void k_gate(const float* __restrict__ h2, const float* __restrict__ gw,
                       const float* __restrict__ gb, float* __restrict__ wout){
  int row = blockIdx.x*4 + (threadIdx.x>>6);
  int lane = threadIdx.x & 63;
  const float* hr = h2 + (size_t)row*C;
  float a0=0,a1=0,a2=0,a3=0;
  for(int c=lane;c<C;c+=64){
    float hv = hr[c];
    const float* g = gw + c*NE;
    a0+=hv*g[0]; a1+=hv*g[1]; a2+=hv*g[2]; a3+=hv*g[3];
  }
  a0=wsum(a0); a1=wsum(a1); a2=wsum(a2); a3=wsum(a3);
  if (lane==0){
    float p[4]={a0+gb[0],a1+gb[1],a2+gb[2],a3+gb[3]};
    float m = fmaxf(fmaxf(p[0],p[1]),fmaxf(p[2],p[3]));
    float s=0.f;
#pragma unroll
    for(int e=0;e<4;e++){ p[e]=expf(p[e]-m); s+=p[e]; }
#pragma unroll
    for(int e=0;e<4;e++) p[e] /= s;
    int i1=0;
    for(int e=1;e<4;e++) if(p[e]>p[i1]) i1=e;
    int i2=-1;
    for(int e=0;e<4;e++){ if(e==i1) continue; if(i2<0 || p[e]>p[i2]) i2=e; }
    float invs = 1.f/(p[i1]+p[i2]+1e-9f);
    float wv[4]={0.f,0.f,0.f,0.f};
    wv[i1]=p[i1]*invs; wv[i2]=p[i2]*invs;
    float* o = wout + (size_t)row*NE;
    o[0]=wv[0]; o[1]=wv[1]; o[2]=wv[2]; o[3]=wv[3];
  }
}

// ---------------- per-expert compaction + inverse map ----------------
__global__ __launch_bounds__(256) void k_compact(const float* __restrict__ wbuf,
    int* __restrict__ ridx, int* __restrict__ posmap, int* __restrict__ cnt){
  int e = blockIdx.x;
  int tid = threadIdx.x;
  int wave = tid>>6, lane = tid&63;
  __shared__ int wsum_s[4];
  __shared__ int base_s;
  if (tid==0) base_s = 0;
  __syncthreads();
  for(int t0=0; t0<NT; t0+=256){
    int t = t0 + tid;
    bool f = wbuf[(size_t)t*NE + e] > 0.f;
    unsigned long long bal = __ballot(f);
    int pre = __popcll(bal & ((1ull<<lane)-1ull));
    if (lane==0) wsum_s[wave] = __popcll(bal);
    __syncthreads();
    int off = 0;
#pragma unroll
    for(int w2=0;w2<4;w2++) if (w2 < wave) off += wsum_s[w2];
    int tot = wsum_s[0]+wsum_s[1]+wsum_s[2]+wsum_s[3];
    int b0 = base_s;
    int pos = b0 + off + pre;
    if (f) ridx[(size_t)e*NT + pos] = t;
    posmap[(size_t)t*NE + e] = f ? pos : -1;
    __syncthreads();
    if (tid==0) base_s = b0 + tot;
    __syncthreads();
  }
  if (tid==0) cnt[e] = base_s;
}

__global__ void k_prefix(const int* __restrict__ cnt, int* __restrict__ ebase){
  if (threadIdx.x==0 && blockIdx.x==0){
    int s=0;
#pragma unroll
    for(int e=0;e<NE;e++){ ebase[e]=s; s+=cnt[e]; }
  }
}

// ---------------- MoE gather: x[t] += sum_e w[t,e] * ye[ebase[e]+pos(t,e)] ----------------
__global__ __launch_bounds__(256) void k_moe_gather(const float* __restrict__ ye,
    const float* __restrict__ wbuf, const int* __restrict__ posmap,
    const int* __restrict__ ebase, float* __restrict__ x){
  int idx = blockIdx.x*256 + threadIdx.x;
  if (idx >= NT*(C/4)) return;
  int t = idx/(C/4), c4 = (idx - t*(C/4))*4;
  float4 acc = *(const float4*)(x + (size_t)t*C + c4);
#pragma unroll
  for(int e=0;e<NE;e++){
    int p = posmap[(size_t)t*NE + e];
    if (p >= 0){
      float w = wbuf[(size_t)t*NE + e];
      float4 yv = *(const float4*)(ye + (size_t)(ebase[e]+p)*C + c4);
      acc.x += w*yv.x; acc.y += w*yv.y; acc.z += w*yv.z; acc.w += w*yv.w;
    }
  }
  *(float4*)(x + (size_t)t*C + c4) = acc;
}

extern "C" void kernel_launch(void* const* d_in, const int* in_sizes, int n_in,
                              void* d_out, int out_size, void* d_ws, size_t ws_size,
                              hipStream_t stream){
  (void)in_sizes; (void)n_in; (void)out_size; (void)ws_size;
  const int*   tokens  = (const int*)d_in[0];
  const float* tok_emb = (const float*)d_in[1];
  const float* pos_emb = (const float*)d_in[2];
  const float* mem     = (const float*)d_in[3];
  const float* ln1_w   = (const float*)d_in[4];
  const float* ln1_b   = (const float*)d_in[5];
  const float* qkv_w   = (const float*)d_in[6];
  const float* qkv_b   = (const float*)d_in[7];
  const float* proj_w  = (const float*)d_in[8];
  const float* proj_b  = (const float*)d_in[9];
  const float* attn_g  = (const float*)d_in[10];
  const float* th1_w   = (const float*)d_in[11];
  const float* th1_b   = (const float*)d_in[12];
  const float* th2_w   = (const float*)d_in[13];
  const float* th2_b   = (const float*)d_in[14];
  const float* ln2_w   = (const float*)d_in[15];
  const float* ln2_b   = (const float*)d_in[16];
  const float* gate_w  = (const float*)d_in[17];
  const float* gate_b  = (const float*)d_in[18];
  const float* e1_w    = (const float*)d_in[19];
  const float* e1_b    = (const float*)d_in[20];
  const float* e2_w    = (const float*)d_in[21];
  const float* e2_b    = (const float*)d_in[22];
  const float* lnf_w   = (const float*)d_in[23];
  const float* lnf_b   = (const float*)d_in[24];
  const float* head_w  = (const float*)d_in[25];
  const float* head_b  = (const float*)d_in[26];
  float* out = (float*)d_out;

  char* p = (char*)d_ws;
  float* x    = (float*)p; p += (size_t)NT*C*4;       // residual
  float* h    = (float*)p; p += (size_t)NT*C*4;       // LN out
  float* qkvb = (float*)p; p += (size_t)NT*N3C*4;     // qkv; aliased by ye (2NT*C)
  float* sh   = (float*)p; p += (size_t)2*NT*FCH*4;   // y / t1 / he_all
  float* wbuf = (float*)p; p += (size_t)NT*NE*4;
  int*   ridx = (int*)p;   p += (size_t)NE*NT*4;
  int*   posm = (int*)p;   p += (size_t)NT*NE*4;
  int*   cnt  = (int*)p;   p += 64;
  int*   ebase= (int*)p;   p += 64;
  float* ye   = qkvb;
  float* he   = sh;

  dim3 b256(256);
  k_embed<<<dim3((NT*C+255)/256), b256, 0, stream>>>(tokens, tok_emb, pos_emb, x);
  for(int l=0;l<LAYERS;l++){
    k_ln<<<dim3(NT/4), b256, 0, stream>>>(x, ln1_w+l*C, ln1_b+l*C, h);
    k_gemm<0,false,false,false,128><<<dim3(N3C/128, NT/128), b256, 0, stream>>>(
        h, qkv_w+(size_t)l*C*N3C, qkv_b+(size_t)l*N3C, nullptr, nullptr, nullptr, 0, 0,
        qkvb, C, C, N3C, N3C);
    k_attn<<<dim3(BB*NH), b256, 0, stream>>>(qkvb, mem, attn_g+(size_t)l*C, sh);
    k_gemm<0,true,false,false,64><<<dim3(C/64, NT/128), b256, 0, stream>>>(
        sh, proj_w+(size_t)l*C*C, proj_b+(size_t)l*C, nullptr, nullptr, nullptr, 0, 0,
        x, C, C, C, C);
    k_gemm<1,false,false,false,64><<<dim3(TD/64, NT/128), b256, 0, stream>>>(
        x, th1_w+(size_t)l*C*TD, th1_b+(size_t)l*TD, nullptr, nullptr, nullptr, 0, 0,
        sh, C, C, TD, TD);
    k_gemm<0,true,false,false,64><<<dim3(C/64, NT/128), b256, 0, stream>>>(
        sh, th2_w+(size_t)l*TD*C, th2_b+(size_t)l*C, nullptr, nullptr, nullptr, 0, 0,
        x, TD, TD, C, C);
    k_ln<<<dim3(NT/4), b256, 0, stream>>>(x, ln2_w+l*C, ln2_b+l*C, h);
    k_gate<<<dim3(NT/4), b256, 0, stream>>>(h, gate_w+(size_t)l*C*NE, gate_b+(size_t)l*NE, wbuf);
    k_compact<<<dim3(NE), b256, 0, stream>>>(wbuf, ridx, posm, cnt);
    k_prefix<<<dim3(1), dim3(64), 0, stream>>>(cnt, ebase);
    for(int f0=0; f0<FF; f0+=FCH){
      k_gemm<2,false,true,true,64><<<dim3(FCH/64, NT/128, NE), b256, 0, stream>>>(
          h, e1_w + (size_t)l*NE*C*FF + f0, e1_b + (size_t)l*NE*FF + f0,
          ridx, cnt, ebase, (size_t)C*FF, (size_t)FF,
          he, C, C, FF, FCH);
      if (f0==0)
        k_gemm<0,false,true,false,64><<<dim3(C/64, NT/128, NE), b256, 0, stream>>>(
            he, e2_w + (size_t)l*NE*FF*C, e2_b + (size_t)l*NE*C,
            ridx, cnt, ebase, (size_t)FF*C, (size_t)C,
            ye, FCH, FCH, C, C);
      else
        k_gemm<0,true,true,false,64><<<dim3(C/64, NT/128, NE), b256, 0, stream>>>(
            he, e2_w + (size_t)l*NE*FF*C + (size_t)f0*C, nullptr,
            ridx, cnt, ebase, (size_t)FF*C, (size_t)C,
            ye, FCH, FCH, C, C);
    }
    k_moe_gather<<<dim3((NT*(C/4)+255)/256), b256, 0, stream>>>(ye, wbuf, posm, ebase, x);
  }
  k_ln<<<dim3(NT/4), b256, 0, stream>>>(x, lnf_w, lnf_b, h);
  k_gemm<0,false,false,false,64><<<dim3(NV/64, NT/128), b256, 0, stream>>>(
      h, head_w, head_b, nullptr, nullptr, nullptr, 0, 0,
      out, C, C, NV, NV);
}